// Round 1
// baseline (431.468 us; speedup 1.0000x reference)
//
#include <hip/hip_runtime.h>
#include <cstdint>
#include <cstddef>

#define BB 2
#define CC 256
#define NN 16
#define LL 4096
#define NCH 128
#define CLEN 32
#define LOG2E 1.4426950408889634f

typedef __attribute__((ext_vector_type(8))) short short8;
typedef __attribute__((ext_vector_type(4))) float f32x4;

__device__ __forceinline__ float softplus_f(float z) {
    return fmaxf(z, 0.f) + log1pf(expf(-fabsf(z)));
}

__device__ __forceinline__ uint32_t pack_bf2(float d, float u) {
    uint32_t lo = (__float_as_uint(d) + 0x8000u) >> 16;
    uint32_t hh = (__float_as_uint(u) + 0x8000u) & 0xffff0000u;
    return hh | lo;
}

__device__ __forceinline__ short bf16r(float f) {
    return (short)((__float_as_uint(f) + 0x8000u) >> 16);
}

// ---------------- K1 (MFMA): Z = X@Wd via bf16 matrix cores -----------------
// grid = 1024 = b(2) x lt(128 l-tiles of 32) x ct(4 c-tiles of 64).
// block = 32l x 64c tile, 256 thr (4 waves: wq -> m0=(wq&1)*16, n0=(wq>>1)*32).
// Fragments loaded DIRECTLY from global fp32 + cvt (no LDS, no barrier):
//   A[m=lane&15][k=quad*8+j] = feat[k][l0+m0+m]  (16 consecutive l per quad)
//   B[k][n=lane&15]          = Wd[k][c0+n0+nt*16+n] (L1/L2-resident)
//   C/D: col=lane&15, row=quad*4+reg  [m89-verified]
// ct==0 blocks also compute Bm/Cm with a 3rd MFMA reusing the A-frag.
__global__ __launch_bounds__(256) void k1_mfma(
    const float* __restrict__ feat, const float* __restrict__ Wd,
    const float* __restrict__ bd, const float* __restrict__ WB,
    const float* __restrict__ WC, uint32_t* __restrict__ du,
    float* __restrict__ Bm, float* __restrict__ Cm)
{
    int blk = blockIdx.x;               // b*512 + lt*4 + ct
    int b  = blk >> 9;
    int lt = (blk >> 2) & 127;
    int ct = blk & 3;
    int l0 = lt * 32, c0 = ct * 64;
    const float* fbase = feat + (size_t)b * CC * LL;
    int lane = threadIdx.x & 63;
    int wq   = threadIdx.x >> 6;
    int m    = lane & 15;
    int quad = lane >> 4;
    int m0   = (wq & 1) * 16;
    int n0   = (wq >> 1) * 32;
    bool doBC = (ct == 0);
    const float* wBC = (wq >> 1) ? WC : WB;

    f32x4 acc0 = {0.f, 0.f, 0.f, 0.f};
    f32x4 acc1 = {0.f, 0.f, 0.f, 0.f};
    f32x4 accB = {0.f, 0.f, 0.f, 0.f};

    const float* aptr  = fbase + (size_t)(quad * 8) * LL + (l0 + m0 + m);
    const float* b0ptr = Wd    + (size_t)(quad * 8) * CC + (c0 + n0 + m);
    const float* b1ptr = b0ptr + 16;
    const float* bbptr = wBC   + (size_t)(quad * 8) * NN + m;

    for (int ks = 0; ks < 8; ++ks) {
        short8 af, bf0, bf1;
        #pragma unroll
        for (int j = 0; j < 8; ++j) {
            size_t kr = (size_t)(ks * 32 + j);
            af[j]  = bf16r(aptr [kr * LL]);
            bf0[j] = bf16r(b0ptr[kr * CC]);
            bf1[j] = bf16r(b1ptr[kr * CC]);
        }
        acc0 = __builtin_amdgcn_mfma_f32_16x16x32_bf16(af, bf0, acc0, 0, 0, 0);
        acc1 = __builtin_amdgcn_mfma_f32_16x16x32_bf16(af, bf1, acc1, 0, 0, 0);
        if (doBC) {
            short8 bbf;
            #pragma unroll
            for (int j = 0; j < 8; ++j)
                bbf[j] = bf16r(bbptr[(size_t)(ks * 32 + j) * NN]);
            accB = __builtin_amdgcn_mfma_f32_16x16x32_bf16(af, bbf, accB, 0, 0, 0);
        }
    }

    if (doBC) {
        float* dst = (wq >> 1) ? Cm : Bm;
        #pragma unroll
        for (int r = 0; r < 4; ++r) {
            int l = l0 + m0 + quad * 4 + r;
            dst[((size_t)b * LL + l) * NN + m] = accB[r];
        }
    }

    float bd0 = bd[c0 + n0 + m];
    float bd1 = bd[c0 + n0 + 16 + m];
    int cA = c0 + n0 + m;
    int cB = cA + 16;
    #pragma unroll
    for (int r = 0; r < 4; ++r) {
        int l = l0 + m0 + quad * 4 + r;
        float d0 = softplus_f(acc0[r] + bd0);
        float d1 = softplus_f(acc1[r] + bd1);
        float x0 = fbase[(size_t)cA * LL + l];
        float x1 = fbase[(size_t)cB * LL + l];
        du[((size_t)b * LL + l) * CC + cA] = pack_bf2(d0, d0 * x0);
        du[((size_t)b * LL + l) * CC + cB] = pack_bf2(d1, d1 * x1);
    }
}

// ---------------- P1: per-chunk aggregates ----------------------------------
// blk<256: FUSED fwd(cls0 chunk ch) + rev(cls1 chunk 127-ch) from ONE du read.
//   - rev S via prefix-product trick (shares the 16 exp2/step with fwd):
//       S_r += pref*u*B ; pref *= dA    (pref = prod of dA over q<j)
//   - P is order-independent (exp2(A2*sum dx)) -> written ONCE to cls0 slot;
//     p2 reads d1's P from cls0[127-ch].
// blk>=256: cls2 (d3 column chunks), unchanged.
__global__ __launch_bounds__(256) void p1_aggr(
    const uint32_t* __restrict__ du, const float* __restrict__ Bm,
    const float* __restrict__ A_log, float* __restrict__ P, float* __restrict__ S)
{
    int blk = blockIdx.x;
    int b  = (blk >> 7) & 1;
    int ch = blk & 127;
    int c = threadIdx.x;
    __shared__ float sBm[CLEN * NN];

    float A2[NN];
    {
        const float4* al = (const float4*)(A_log + c * NN);
        #pragma unroll
        for (int q = 0; q < 4; ++q) {
            float4 v = al[q];
            A2[q*4+0] = -expf(v.x) * LOG2E;
            A2[q*4+1] = -expf(v.y) * LOG2E;
            A2[q*4+2] = -expf(v.z) * LOG2E;
            A2[q*4+3] = -expf(v.w) * LOG2E;
        }
    }

    if (blk < 256) {
        int p0 = 32 * ch;
        for (int i = threadIdx.x; i < CLEN * NN; i += 256) {
            int j = i >> 4, nn = i & 15;
            sBm[i] = Bm[((size_t)b * LL + (p0 + j)) * NN + nn];
        }
        const uint32_t* dub = du + (size_t)b * LL * CC + c;
        uint32_t w[CLEN];
        #pragma unroll
        for (int j = 0; j < CLEN; ++j)
            w[j] = dub[(size_t)(p0 + j) * CC];
        __syncthreads();
        float Sf[NN] = {}, Sr[NN] = {}, pref[NN];
        #pragma unroll
        for (int nn = 0; nn < NN; ++nn) pref[nn] = 1.f;
        float sumd = 0.f;
        #pragma unroll
        for (int j = 0; j < CLEN; ++j) {
            float dx = __uint_as_float(w[j] << 16);
            float uy = __uint_as_float(w[j] & 0xffff0000u);
            sumd += dx;
            float dA[NN];
            #pragma unroll
            for (int nn = 0; nn < NN; ++nn) dA[nn] = __builtin_amdgcn_exp2f(A2[nn] * dx);
            #pragma unroll
            for (int nn = 0; nn < NN; ++nn) {
                float Bu = uy * sBm[j * 16 + nn];
                Sf[nn] = fmaf(dA[nn], Sf[nn], Bu);
                Sr[nn] = fmaf(pref[nn], Bu, Sr[nn]);
                pref[nn] *= dA[nn];
            }
        }
        size_t base0 = ((size_t)(b * 128 + ch)) * 4096 + (size_t)c * 16;
        size_t base1 = ((size_t)((2 + b) * 128 + (127 - ch))) * 4096 + (size_t)c * 16;
        #pragma unroll
        for (int nn = 0; nn < NN; ++nn) {
            P[base0 + nn] = __builtin_amdgcn_exp2f(A2[nn] * sumd);
            S[base0 + nn] = Sf[nn];
            S[base1 + nn] = Sr[nn];
        }
    } else {
        // cls2: d3 column chunks (inner stride 64)
        int p0 = 63 - (ch >> 1) + 2048 * (ch & 1);
        const int inner = 64;
        for (int i = threadIdx.x; i < CLEN * NN; i += 256) {
            int j = i >> 4, nn = i & 15;
            sBm[i] = Bm[((size_t)b * LL + (p0 + inner * j)) * NN + nn];
        }
        const uint32_t* dub = du + (size_t)b * LL * CC + c;
        uint32_t w[CLEN];
        #pragma unroll
        for (int j = 0; j < CLEN; ++j)
            w[j] = dub[(size_t)(p0 + inner * j) * CC];
        __syncthreads();
        float Sv[NN] = {};
        float sumd = 0.f;
        #pragma unroll
        for (int j = 0; j < CLEN; ++j) {
            float dx = __uint_as_float(w[j] << 16);
            float uy = __uint_as_float(w[j] & 0xffff0000u);
            sumd += dx;
            float dA[NN];
            #pragma unroll
            for (int nn = 0; nn < NN; ++nn) dA[nn] = __builtin_amdgcn_exp2f(A2[nn] * dx);
            #pragma unroll
            for (int nn = 0; nn < NN; ++nn)
                Sv[nn] = fmaf(dA[nn], Sv[nn], uy * sBm[j * 16 + nn]);
        }
        size_t base = ((size_t)((4 + b) * 128 + ch)) * 4096 + (size_t)c * 16;
        #pragma unroll
        for (int nn = 0; nn < NN; ++nn) {
            P[base + nn] = __builtin_amdgcn_exp2f(A2[nn] * sumd);
            S[base + nn] = Sv[nn];
        }
    }
}

// ---------------- P2: scan chunk aggregates per direction -> Hin ------------
// d1's P comes from cls0 slot [127-ch] (p1 no longer writes cls1 P).
__global__ __launch_bounds__(128) void p2_scan(
    const float* __restrict__ P, const float* __restrict__ S, float* __restrict__ Hin)
{
    int r = blockIdx.x * 128 + threadIdx.x;   // 32768 rows
    int cn = r & 4095;
    int db = r >> 12;
    int d = db >> 1;
    int cls = (d == 1) ? 1 : ((d == 3) ? 2 : 0);
    int b = db & 1;
    const size_t sbase = ((size_t)(cls * 2 + b) * 128) * 4096 + cn;
    const size_t pbase = (d == 1) ? (((size_t)b * 128) * 4096 + cn) : sbase;
    const size_t obase = ((size_t)db * 128) * 4096 + cn;
    float h = 0.f;
    for (int g = 0; g < 16; ++g) {
        float pv[8], sv[8];
        #pragma unroll
        for (int i = 0; i < 8; ++i) {
            int ch = g * 8 + i;
            int chm = (d == 2) ? (126 - 2 * (ch >> 1) + (ch & 1)) : ch;
            int chp = (d == 1) ? (127 - ch) : chm;
            pv[i] = P[pbase + (size_t)chp * 4096];
            sv[i] = S[sbase + (size_t)chm * 4096];
        }
        #pragma unroll
        for (int i = 0; i < 8; ++i) {
            Hin[obase + (size_t)(g * 8 + i) * 4096] = h;
            h = fmaf(pv[i], h, sv[i]);
        }
    }
}

// ---------------- P3: replay --------------------------------------------
// blk<256: FUSED d0+d2 (forward) + d1 (backward) on one du/Bm/Cm read.
//   backward pass first: h1 from Hin[d1 chunk 127-ch], j=31..0, y1v[32] regs;
//   forward pass then writes yAB = 0.25*(y0+y2+y1).
// blk>=256: d3 column replay -> yC (unchanged).
__global__ __launch_bounds__(256) void p3_replay(
    const uint32_t* __restrict__ du, const float* __restrict__ Bm,
    const float* __restrict__ Cm, const float* __restrict__ A_log,
    const float* __restrict__ Hin, float* __restrict__ yAB,
    float* __restrict__ yC)
{
    int blk = blockIdx.x;
    int b  = (blk >> 7) & 1;
    int ch = blk & 127;
    int c = threadIdx.x;
    __shared__ float sBm[CLEN * NN];
    __shared__ float sCm[CLEN * NN];

    float A2[NN];
    {
        const float4* al = (const float4*)(A_log + c * NN);
        #pragma unroll
        for (int q = 0; q < 4; ++q) {
            float4 v = al[q];
            A2[q*4+0] = -expf(v.x) * LOG2E;
            A2[q*4+1] = -expf(v.y) * LOG2E;
            A2[q*4+2] = -expf(v.z) * LOG2E;
            A2[q*4+3] = -expf(v.w) * LOG2E;
        }
    }

    if (blk < 256) {
        int p0 = 32 * ch;
        for (int i = threadIdx.x; i < CLEN * NN; i += 256) {
            int j = i >> 4, nn = i & 15;
            size_t o = ((size_t)b * LL + (p0 + j)) * NN + nn;
            sBm[i] = Bm[o];
            sCm[i] = Cm[o];
        }
        const uint32_t* dub = du + (size_t)b * LL * CC + c;
        uint32_t w[CLEN];
        #pragma unroll
        for (int j = 0; j < CLEN; ++j)
            w[j] = dub[(size_t)(p0 + j) * CC];

        int ch2 = 126 - (ch & ~1) + (ch & 1);   // d2 scan-position of this chunk
        int chr = 127 - ch;                     // d1 chunk covering same l-set
        float h0[NN], h1[NN], h2[NN];
        {
            const float4* hp0 = (const float4*)(Hin + ((size_t)(0 * 2 + b) * 128 + ch)  * 4096 + (size_t)c * 16);
            const float4* hp1 = (const float4*)(Hin + ((size_t)(1 * 2 + b) * 128 + chr) * 4096 + (size_t)c * 16);
            const float4* hp2 = (const float4*)(Hin + ((size_t)(2 * 2 + b) * 128 + ch2) * 4096 + (size_t)c * 16);
            #pragma unroll
            for (int q = 0; q < 4; ++q) {
                float4 v0 = hp0[q], v1 = hp1[q], v2 = hp2[q];
                h0[q*4+0]=v0.x; h0[q*4+1]=v0.y; h0[q*4+2]=v0.z; h0[q*4+3]=v0.w;
                h1[q*4+0]=v1.x; h1[q*4+1]=v1.y; h1[q*4+2]=v1.z; h1[q*4+3]=v1.w;
                h2[q*4+0]=v2.x; h2[q*4+1]=v2.y; h2[q*4+2]=v2.z; h2[q*4+3]=v2.w;
            }
        }
        __syncthreads();

        // --- backward pass: d1 (l decreasing == j 31..0) ---
        float y1v[CLEN];
        #pragma unroll
        for (int j = CLEN - 1; j >= 0; --j) {
            float dx = __uint_as_float(w[j] << 16);
            float uy = __uint_as_float(w[j] & 0xffff0000u);
            float dA[NN];
            #pragma unroll
            for (int nn = 0; nn < NN; ++nn) dA[nn] = __builtin_amdgcn_exp2f(A2[nn] * dx);
            float yv = 0.f;
            #pragma unroll
            for (int nn = 0; nn < NN; ++nn) {
                float Bu = uy * sBm[j * 16 + nn];
                h1[nn] = fmaf(dA[nn], h1[nn], Bu);
                yv = fmaf(h1[nn], sCm[j * 16 + nn], yv);
            }
            y1v[j] = yv;
        }

        // --- forward pass: d0 + d2, fold in y1 ---
        #pragma unroll
        for (int j = 0; j < CLEN; ++j) {
            float dx = __uint_as_float(w[j] << 16);
            float uy = __uint_as_float(w[j] & 0xffff0000u);
            float dA[NN];
            #pragma unroll
            for (int nn = 0; nn < NN; ++nn) dA[nn] = __builtin_amdgcn_exp2f(A2[nn] * dx);
            float y0v = 0.f, y2v = 0.f;
            #pragma unroll
            for (int nn = 0; nn < NN; ++nn) {
                float Bu = uy * sBm[j * 16 + nn];
                float cm = sCm[j * 16 + nn];
                h0[nn] = fmaf(dA[nn], h0[nn], Bu);
                h2[nn] = fmaf(dA[nn], h2[nn], Bu);
                y0v = fmaf(h0[nn], cm, y0v);
                y2v = fmaf(h2[nn], cm, y2v);
            }
            yAB[((size_t)b * LL + p0 + j) * CC + c] = 0.25f * (y0v + y2v + y1v[j]);
        }
    } else {
        // d3 column replay
        int p0 = 63 - (ch >> 1) + 2048 * (ch & 1);
        const int inner = 64;
        for (int i = threadIdx.x; i < CLEN * NN; i += 256) {
            int j = i >> 4, nn = i & 15;
            size_t o = ((size_t)b * LL + (p0 + inner * j)) * NN + nn;
            sBm[i] = Bm[o];
            sCm[i] = Cm[o];
        }
        const uint32_t* dub = du + (size_t)b * LL * CC + c;
        uint32_t w[CLEN];
        #pragma unroll
        for (int j = 0; j < CLEN; ++j)
            w[j] = dub[(size_t)(p0 + inner * j) * CC];
        float h[NN];
        {
            const float4* hp = (const float4*)(Hin + ((size_t)(3 * 2 + b) * 128 + ch) * 4096 + (size_t)c * 16);
            #pragma unroll
            for (int q = 0; q < 4; ++q) {
                float4 v = hp[q];
                h[q*4+0]=v.x; h[q*4+1]=v.y; h[q*4+2]=v.z; h[q*4+3]=v.w;
            }
        }
        __syncthreads();
        #pragma unroll
        for (int j = 0; j < CLEN; ++j) {
            float dx = __uint_as_float(w[j] << 16);
            float uy = __uint_as_float(w[j] & 0xffff0000u);
            float dA[NN];
            #pragma unroll
            for (int nn = 0; nn < NN; ++nn) dA[nn] = __builtin_amdgcn_exp2f(A2[nn] * dx);
            float yv = 0.f;
            #pragma unroll
            for (int nn = 0; nn < NN; ++nn) {
                float Bu = uy * sBm[j * 16 + nn];
                h[nn] = fmaf(dA[nn], h[nn], Bu);
                yv = fmaf(h[nn], sCm[j * 16 + nn], yv);
            }
            yC[((size_t)b * LL + p0 + inner * j) * CC + c] = 0.25f * yv;
        }
    }
}

// ---------------- K6: sum 2 y-buffers + x*D, transpose to (B,C,L) -----------
__global__ __launch_bounds__(256) void k6_reduce(
    const float* __restrict__ feat, const float* __restrict__ D,
    const float* __restrict__ yAB, const float* __restrict__ yC,
    float* __restrict__ out)
{
    int pt = blockIdx.x & 63;
    int ct = (blockIdx.x >> 6) & 3;
    int b  = blockIdx.x >> 8;
    int p0 = pt * 64, c0 = ct * 64;
    __shared__ float tile[64 * 65];
    {
        int cl = threadIdx.x & 63;
        int pg = threadIdx.x >> 6;
        #pragma unroll
        for (int pp = 0; pp < 16; ++pp) {
            int pl = pp * 4 + pg;
            size_t ix = ((size_t)b * LL + p0 + pl) * CC + c0 + cl;
            tile[cl * 65 + pl] = yAB[ix] + yC[ix];
        }
    }
    __syncthreads();
    {
        int pl = threadIdx.x & 63;
        int cg = threadIdx.x >> 6;
        #pragma unroll
        for (int cc = 0; cc < 16; ++cc) {
            int cloc = cc * 4 + cg;
            int c = c0 + cloc;
            size_t o = ((size_t)b * CC + c) * LL + p0 + pl;
            out[o] = tile[cloc * 65 + pl] + feat[o] * D[c];
        }
    }
}

extern "C" void kernel_launch(void* const* d_in, const int* in_sizes, int n_in,
                              void* d_out, int out_size, void* d_ws, size_t ws_size,
                              hipStream_t stream)
{
    const float* feat  = (const float*)d_in[0];
    const float* A_log = (const float*)d_in[1];
    const float* D     = (const float*)d_in[2];
    const float* Wd    = (const float*)d_in[3];
    const float* bd    = (const float*)d_in[4];
    const float* WB    = (const float*)d_in[5];
    const float* WC    = (const float*)d_in[6];
    float* out = (float*)d_out;

    float* ws  = (float*)d_ws;
    uint32_t* du = (uint32_t*)ws;                         //  2,097,152 u32 (bf16x2)
    float* Bm  = ws  + (size_t)2097152;                   //    131,072
    float* Cm  = Bm  + (size_t)131072;                    //    131,072
    float* P   = Cm  + (size_t)131072;                    //  3,145,728 (3 cls; cls1 P unused)
    float* S   = P   + (size_t)3145728;                   //  3,145,728
    float* Hin = S   + (size_t)3145728;                   //  4,194,304 (4 dirs)
    float* yAB = Hin + (size_t)4194304;                   //  2,097,152
    float* yC  = yAB + (size_t)2097152;                   //  2,097,152

    k1_mfma<<<1024, 256, 0, stream>>>(feat, Wd, bd, WB, WC, du, Bm, Cm);
    p1_aggr<<<512, 256, 0, stream>>>(du, Bm, A_log, P, S);
    p2_scan<<<256, 128, 0, stream>>>(P, S, Hin);
    p3_replay<<<512, 256, 0, stream>>>(du, Bm, Cm, A_log, Hin, yAB, yC);
    k6_reduce<<<512, 256, 0, stream>>>(feat, D, yAB, yC, out);
}

// Round 3
// 183.934 us; speedup vs baseline: 2.3458x; 2.3458x over previous
//
#include <hip/hip_runtime.h>
#include <cstdint>
#include <cstddef>

#define BB 2
#define CC 256
#define NN 16
#define LL 4096
#define NCH 128
#define CLEN 32
#define LOG2E 1.4426950408889634f

typedef __attribute__((ext_vector_type(8))) short short8;
typedef __attribute__((ext_vector_type(4))) float f32x4;

__device__ __forceinline__ float softplus_f(float z) {
    return fmaxf(z, 0.f) + log1pf(expf(-fabsf(z)));
}

__device__ __forceinline__ uint32_t pack_bf2(float d, float u) {
    uint32_t lo = (__float_as_uint(d) + 0x8000u) >> 16;
    uint32_t hh = (__float_as_uint(u) + 0x8000u) & 0xffff0000u;
    return hh | lo;
}

__device__ __forceinline__ short bf16r(float f) {
    return (short)((__float_as_uint(f) + 0x8000u) >> 16);
}

// ---------------- K1 (MFMA): Z = X@Wd via bf16 matrix cores -----------------
__global__ __launch_bounds__(256) void k1_mfma(
    const float* __restrict__ feat, const float* __restrict__ Wd,
    const float* __restrict__ bd, const float* __restrict__ WB,
    const float* __restrict__ WC, uint32_t* __restrict__ du,
    float* __restrict__ Bm, float* __restrict__ Cm)
{
    int blk = blockIdx.x;               // b*512 + lt*4 + ct
    int b  = blk >> 9;
    int lt = (blk >> 2) & 127;
    int ct = blk & 3;
    int l0 = lt * 32, c0 = ct * 64;
    const float* fbase = feat + (size_t)b * CC * LL;
    int lane = threadIdx.x & 63;
    int wq   = threadIdx.x >> 6;
    int m    = lane & 15;
    int quad = lane >> 4;
    int m0   = (wq & 1) * 16;
    int n0   = (wq >> 1) * 32;
    bool doBC = (ct == 0);
    const float* wBC = (wq >> 1) ? WC : WB;

    f32x4 acc0 = {0.f, 0.f, 0.f, 0.f};
    f32x4 acc1 = {0.f, 0.f, 0.f, 0.f};
    f32x4 accB = {0.f, 0.f, 0.f, 0.f};

    const float* aptr  = fbase + (size_t)(quad * 8) * LL + (l0 + m0 + m);
    const float* b0ptr = Wd    + (size_t)(quad * 8) * CC + (c0 + n0 + m);
    const float* b1ptr = b0ptr + 16;
    const float* bbptr = wBC   + (size_t)(quad * 8) * NN + m;

    for (int ks = 0; ks < 8; ++ks) {
        short8 af, bf0, bf1;
        #pragma unroll
        for (int j = 0; j < 8; ++j) {
            size_t kr = (size_t)(ks * 32 + j);
            af[j]  = bf16r(aptr [kr * LL]);
            bf0[j] = bf16r(b0ptr[kr * CC]);
            bf1[j] = bf16r(b1ptr[kr * CC]);
        }
        acc0 = __builtin_amdgcn_mfma_f32_16x16x32_bf16(af, bf0, acc0, 0, 0, 0);
        acc1 = __builtin_amdgcn_mfma_f32_16x16x32_bf16(af, bf1, acc1, 0, 0, 0);
        if (doBC) {
            short8 bbf;
            #pragma unroll
            for (int j = 0; j < 8; ++j)
                bbf[j] = bf16r(bbptr[(size_t)(ks * 32 + j) * NN]);
            accB = __builtin_amdgcn_mfma_f32_16x16x32_bf16(af, bbf, accB, 0, 0, 0);
        }
    }

    if (doBC) {
        float* dst = (wq >> 1) ? Cm : Bm;
        #pragma unroll
        for (int r = 0; r < 4; ++r) {
            int l = l0 + m0 + quad * 4 + r;
            dst[((size_t)b * LL + l) * NN + m] = accB[r];
        }
    }

    float bd0 = bd[c0 + n0 + m];
    float bd1 = bd[c0 + n0 + 16 + m];
    int cA = c0 + n0 + m;
    int cB = cA + 16;
    #pragma unroll
    for (int r = 0; r < 4; ++r) {
        int l = l0 + m0 + quad * 4 + r;
        float d0 = softplus_f(acc0[r] + bd0);
        float d1 = softplus_f(acc1[r] + bd1);
        float x0 = fbase[(size_t)cA * LL + l];
        float x1 = fbase[(size_t)cB * LL + l];
        du[((size_t)b * LL + l) * CC + cA] = pack_bf2(d0, d0 * x0);
        du[((size_t)b * LL + l) * CC + cB] = pack_bf2(d1, d1 * x1);
    }
}

// ---------------- P1: per-chunk aggregates ----------------------------------
// blk<256: FUSED fwd(cls0 chunk ch) + rev(cls1 chunk 127-ch) from ONE du read.
//   rev S via prefix-product (shares the 16 exp2/step with fwd).
//   P is order-independent -> written ONCE to cls0 slot; p2 redirects d1's P.
// blk>=256: cls2 (d3 column chunks).
__global__ __launch_bounds__(256) void p1_aggr(
    const uint32_t* __restrict__ du, const float* __restrict__ Bm,
    const float* __restrict__ A_log, float* __restrict__ P, float* __restrict__ S)
{
    int blk = blockIdx.x;
    int b  = (blk >> 7) & 1;
    int ch = blk & 127;
    int c = threadIdx.x;
    __shared__ float sBm[CLEN * NN];

    float A2[NN];
    {
        const float4* al = (const float4*)(A_log + c * NN);
        #pragma unroll
        for (int q = 0; q < 4; ++q) {
            float4 v = al[q];
            A2[q*4+0] = -expf(v.x) * LOG2E;
            A2[q*4+1] = -expf(v.y) * LOG2E;
            A2[q*4+2] = -expf(v.z) * LOG2E;
            A2[q*4+3] = -expf(v.w) * LOG2E;
        }
    }

    if (blk < 256) {
        int p0 = 32 * ch;
        for (int i = threadIdx.x; i < CLEN * NN; i += 256) {
            int j = i >> 4, nn = i & 15;
            sBm[i] = Bm[((size_t)b * LL + (p0 + j)) * NN + nn];
        }
        const uint32_t* dub = du + (size_t)b * LL * CC + c;
        uint32_t w[CLEN];
        #pragma unroll
        for (int j = 0; j < CLEN; ++j)
            w[j] = dub[(size_t)(p0 + j) * CC];
        __syncthreads();
        float Sf[NN] = {}, Sr[NN] = {}, pref[NN];
        #pragma unroll
        for (int nn = 0; nn < NN; ++nn) pref[nn] = 1.f;
        float sumd = 0.f;
        #pragma unroll
        for (int j = 0; j < CLEN; ++j) {
            float dx = __uint_as_float(w[j] << 16);
            float uy = __uint_as_float(w[j] & 0xffff0000u);
            sumd += dx;
            float dA[NN];
            #pragma unroll
            for (int nn = 0; nn < NN; ++nn) dA[nn] = __builtin_amdgcn_exp2f(A2[nn] * dx);
            #pragma unroll
            for (int nn = 0; nn < NN; ++nn) {
                float Bu = uy * sBm[j * 16 + nn];
                Sf[nn] = fmaf(dA[nn], Sf[nn], Bu);
                Sr[nn] = fmaf(pref[nn], Bu, Sr[nn]);
                pref[nn] *= dA[nn];
            }
        }
        size_t base0 = ((size_t)(b * 128 + ch)) * 4096 + (size_t)c * 16;
        size_t base1 = ((size_t)((2 + b) * 128 + (127 - ch))) * 4096 + (size_t)c * 16;
        #pragma unroll
        for (int nn = 0; nn < NN; ++nn) {
            P[base0 + nn] = __builtin_amdgcn_exp2f(A2[nn] * sumd);
            S[base0 + nn] = Sf[nn];
            S[base1 + nn] = Sr[nn];
        }
    } else {
        // cls2: d3 column chunks (inner stride 64)
        int p0 = 63 - (ch >> 1) + 2048 * (ch & 1);
        const int inner = 64;
        for (int i = threadIdx.x; i < CLEN * NN; i += 256) {
            int j = i >> 4, nn = i & 15;
            sBm[i] = Bm[((size_t)b * LL + (p0 + inner * j)) * NN + nn];
        }
        const uint32_t* dub = du + (size_t)b * LL * CC + c;
        uint32_t w[CLEN];
        #pragma unroll
        for (int j = 0; j < CLEN; ++j)
            w[j] = dub[(size_t)(p0 + inner * j) * CC];
        __syncthreads();
        float Sv[NN] = {};
        float sumd = 0.f;
        #pragma unroll
        for (int j = 0; j < CLEN; ++j) {
            float dx = __uint_as_float(w[j] << 16);
            float uy = __uint_as_float(w[j] & 0xffff0000u);
            sumd += dx;
            float dA[NN];
            #pragma unroll
            for (int nn = 0; nn < NN; ++nn) dA[nn] = __builtin_amdgcn_exp2f(A2[nn] * dx);
            #pragma unroll
            for (int nn = 0; nn < NN; ++nn)
                Sv[nn] = fmaf(dA[nn], Sv[nn], uy * sBm[j * 16 + nn]);
        }
        size_t base = ((size_t)((4 + b) * 128 + ch)) * 4096 + (size_t)c * 16;
        #pragma unroll
        for (int nn = 0; nn < NN; ++nn) {
            P[base + nn] = __builtin_amdgcn_exp2f(A2[nn] * sumd);
            S[base + nn] = Sv[nn];
        }
    }
}

// ---------------- P2: scan chunk aggregates per direction -> Hin ------------
__global__ __launch_bounds__(128) void p2_scan(
    const float* __restrict__ P, const float* __restrict__ S, float* __restrict__ Hin)
{
    int r = blockIdx.x * 128 + threadIdx.x;   // 32768 rows
    int cn = r & 4095;
    int db = r >> 12;
    int d = db >> 1;
    int cls = (d == 1) ? 1 : ((d == 3) ? 2 : 0);
    int b = db & 1;
    const size_t sbase = ((size_t)(cls * 2 + b) * 128) * 4096 + cn;
    const size_t pbase = (d == 1) ? (((size_t)b * 128) * 4096 + cn) : sbase;
    const size_t obase = ((size_t)db * 128) * 4096 + cn;
    float h = 0.f;
    for (int g = 0; g < 16; ++g) {
        float pv[8], sv[8];
        #pragma unroll
        for (int i = 0; i < 8; ++i) {
            int ch = g * 8 + i;
            int chm = (d == 2) ? (126 - 2 * (ch >> 1) + (ch & 1)) : ch;
            int chp = (d == 1) ? (127 - ch) : chm;
            pv[i] = P[pbase + (size_t)chp * 4096];
            sv[i] = S[sbase + (size_t)chm * 4096];
        }
        #pragma unroll
        for (int i = 0; i < 8; ++i) {
            Hin[obase + (size_t)(g * 8 + i) * 4096] = h;
            h = fmaf(pv[i], h, sv[i]);
        }
    }
}

// ---------------- P3: replay ------------------------------------------------
// blk<256: FUSED d0+d2 (forward) + d1 (backward) on one du/Bm/Cm read.
//   Register-pressure discipline (R1 post-mortem: y1v[32]+h0/h1/h2 all live ->
//   256 VGPR, 500MB scratch spill, 309us):
//     - backward y1 results go to LDS sY[32][256] (per-thread slot, lane
//       stride-1 = conflict-free), not registers
//     - h0/h2 Hin loads DEFERRED until after the backward pass (liveness
//       split: bwd holds only h1[16], fwd only h0[16]+h2[16])
//     - __syncthreads between passes forces LDS materialization so the
//       compiler can't forward sY through 32 registers
// blk>=256: d3 column replay -> yC.
__global__ __launch_bounds__(256) void p3_replay(
    const uint32_t* __restrict__ du, const float* __restrict__ Bm,
    const float* __restrict__ Cm, const float* __restrict__ A_log,
    const float* __restrict__ Hin, float* __restrict__ yAB,
    float* __restrict__ yC)
{
    int blk = blockIdx.x;
    int b  = (blk >> 7) & 1;
    int ch = blk & 127;
    int c = threadIdx.x;
    __shared__ float sBm[CLEN * NN];
    __shared__ float sCm[CLEN * NN];
    __shared__ float sY[CLEN * 256];

    float A2[NN];
    {
        const float4* al = (const float4*)(A_log + c * NN);
        #pragma unroll
        for (int q = 0; q < 4; ++q) {
            float4 v = al[q];
            A2[q*4+0] = -expf(v.x) * LOG2E;
            A2[q*4+1] = -expf(v.y) * LOG2E;
            A2[q*4+2] = -expf(v.z) * LOG2E;
            A2[q*4+3] = -expf(v.w) * LOG2E;
        }
    }

    if (blk < 256) {
        int p0 = 32 * ch;
        for (int i = threadIdx.x; i < CLEN * NN; i += 256) {
            int j = i >> 4, nn = i & 15;
            size_t o = ((size_t)b * LL + (p0 + j)) * NN + nn;
            sBm[i] = Bm[o];
            sCm[i] = Cm[o];
        }
        const uint32_t* dub = du + (size_t)b * LL * CC + c;
        uint32_t w[CLEN];
        #pragma unroll
        for (int j = 0; j < CLEN; ++j)
            w[j] = dub[(size_t)(p0 + j) * CC];

        // --- backward pass: d1 (l decreasing == j 31..0); only h1 live ---
        int chr = 127 - ch;                     // d1 chunk covering same l-set
        float h1[NN];
        {
            const float4* hp1 = (const float4*)(Hin + ((size_t)(1 * 2 + b) * 128 + chr) * 4096 + (size_t)c * 16);
            #pragma unroll
            for (int q = 0; q < 4; ++q) {
                float4 v1 = hp1[q];
                h1[q*4+0]=v1.x; h1[q*4+1]=v1.y; h1[q*4+2]=v1.z; h1[q*4+3]=v1.w;
            }
        }
        __syncthreads();
        #pragma unroll
        for (int j = CLEN - 1; j >= 0; --j) {
            float dx = __uint_as_float(w[j] << 16);
            float uy = __uint_as_float(w[j] & 0xffff0000u);
            float dA[NN];
            #pragma unroll
            for (int nn = 0; nn < NN; ++nn) dA[nn] = __builtin_amdgcn_exp2f(A2[nn] * dx);
            float yv = 0.f;
            #pragma unroll
            for (int nn = 0; nn < NN; ++nn) {
                float Bu = uy * sBm[j * 16 + nn];
                h1[nn] = fmaf(dA[nn], h1[nn], Bu);
                yv = fmaf(h1[nn], sCm[j * 16 + nn], yv);
            }
            sY[j * 256 + c] = yv;
        }
        __syncthreads();   // materialize sY; kills register-forwarding

        // --- forward pass: d0 + d2; h1 dead, load h0/h2 now ---
        __builtin_amdgcn_sched_barrier(0);
        int ch2 = 126 - (ch & ~1) + (ch & 1);   // d2 scan-position of this chunk
        float h0[NN], h2[NN];
        {
            const float4* hp0 = (const float4*)(Hin + ((size_t)(0 * 2 + b) * 128 + ch)  * 4096 + (size_t)c * 16);
            const float4* hp2 = (const float4*)(Hin + ((size_t)(2 * 2 + b) * 128 + ch2) * 4096 + (size_t)c * 16);
            #pragma unroll
            for (int q = 0; q < 4; ++q) {
                float4 v0 = hp0[q], v2 = hp2[q];
                h0[q*4+0]=v0.x; h0[q*4+1]=v0.y; h0[q*4+2]=v0.z; h0[q*4+3]=v0.w;
                h2[q*4+0]=v2.x; h2[q*4+1]=v2.y; h2[q*4+2]=v2.z; h2[q*4+3]=v2.w;
            }
        }
        #pragma unroll
        for (int j = 0; j < CLEN; ++j) {
            float dx = __uint_as_float(w[j] << 16);
            float uy = __uint_as_float(w[j] & 0xffff0000u);
            float dA[NN];
            #pragma unroll
            for (int nn = 0; nn < NN; ++nn) dA[nn] = __builtin_amdgcn_exp2f(A2[nn] * dx);
            float y0v = 0.f, y2v = 0.f;
            #pragma unroll
            for (int nn = 0; nn < NN; ++nn) {
                float Bu = uy * sBm[j * 16 + nn];
                float cm = sCm[j * 16 + nn];
                h0[nn] = fmaf(dA[nn], h0[nn], Bu);
                h2[nn] = fmaf(dA[nn], h2[nn], Bu);
                y0v = fmaf(h0[nn], cm, y0v);
                y2v = fmaf(h2[nn], cm, y2v);
            }
            yAB[((size_t)b * LL + p0 + j) * CC + c] = 0.25f * (y0v + y2v + sY[j * 256 + c]);
        }
    } else {
        // d3 column replay
        int p0 = 63 - (ch >> 1) + 2048 * (ch & 1);
        const int inner = 64;
        for (int i = threadIdx.x; i < CLEN * NN; i += 256) {
            int j = i >> 4, nn = i & 15;
            size_t o = ((size_t)b * LL + (p0 + inner * j)) * NN + nn;
            sBm[i] = Bm[o];
            sCm[i] = Cm[o];
        }
        const uint32_t* dub = du + (size_t)b * LL * CC + c;
        uint32_t w[CLEN];
        #pragma unroll
        for (int j = 0; j < CLEN; ++j)
            w[j] = dub[(size_t)(p0 + inner * j) * CC];
        float h[NN];
        {
            const float4* hp = (const float4*)(Hin + ((size_t)(3 * 2 + b) * 128 + ch) * 4096 + (size_t)c * 16);
            #pragma unroll
            for (int q = 0; q < 4; ++q) {
                float4 v = hp[q];
                h[q*4+0]=v.x; h[q*4+1]=v.y; h[q*4+2]=v.z; h[q*4+3]=v.w;
            }
        }
        __syncthreads();
        #pragma unroll
        for (int j = 0; j < CLEN; ++j) {
            float dx = __uint_as_float(w[j] << 16);
            float uy = __uint_as_float(w[j] & 0xffff0000u);
            float dA[NN];
            #pragma unroll
            for (int nn = 0; nn < NN; ++nn) dA[nn] = __builtin_amdgcn_exp2f(A2[nn] * dx);
            float yv = 0.f;
            #pragma unroll
            for (int nn = 0; nn < NN; ++nn) {
                float Bu = uy * sBm[j * 16 + nn];
                h[nn] = fmaf(dA[nn], h[nn], Bu);
                yv = fmaf(h[nn], sCm[j * 16 + nn], yv);
            }
            yC[((size_t)b * LL + p0 + inner * j) * CC + c] = 0.25f * yv;
        }
    }
}

// ---------------- K6: sum 2 y-buffers + x*D, transpose to (B,C,L) -----------
__global__ __launch_bounds__(256) void k6_reduce(
    const float* __restrict__ feat, const float* __restrict__ D,
    const float* __restrict__ yAB, const float* __restrict__ yC,
    float* __restrict__ out)
{
    int pt = blockIdx.x & 63;
    int ct = (blockIdx.x >> 6) & 3;
    int b  = blockIdx.x >> 8;
    int p0 = pt * 64, c0 = ct * 64;
    __shared__ float tile[64 * 65];
    {
        int cl = threadIdx.x & 63;
        int pg = threadIdx.x >> 6;
        #pragma unroll
        for (int pp = 0; pp < 16; ++pp) {
            int pl = pp * 4 + pg;
            size_t ix = ((size_t)b * LL + p0 + pl) * CC + c0 + cl;
            tile[cl * 65 + pl] = yAB[ix] + yC[ix];
        }
    }
    __syncthreads();
    {
        int pl = threadIdx.x & 63;
        int cg = threadIdx.x >> 6;
        #pragma unroll
        for (int cc = 0; cc < 16; ++cc) {
            int cloc = cc * 4 + cg;
            int c = c0 + cloc;
            size_t o = ((size_t)b * CC + c) * LL + p0 + pl;
            out[o] = tile[cloc * 65 + pl] + feat[o] * D[c];
        }
    }
}

extern "C" void kernel_launch(void* const* d_in, const int* in_sizes, int n_in,
                              void* d_out, int out_size, void* d_ws, size_t ws_size,
                              hipStream_t stream)
{
    const float* feat  = (const float*)d_in[0];
    const float* A_log = (const float*)d_in[1];
    const float* D     = (const float*)d_in[2];
    const float* Wd    = (const float*)d_in[3];
    const float* bd    = (const float*)d_in[4];
    const float* WB    = (const float*)d_in[5];
    const float* WC    = (const float*)d_in[6];
    float* out = (float*)d_out;

    float* ws  = (float*)d_ws;
    uint32_t* du = (uint32_t*)ws;                         //  2,097,152 u32 (bf16x2)
    float* Bm  = ws  + (size_t)2097152;                   //    131,072
    float* Cm  = Bm  + (size_t)131072;                    //    131,072
    float* P   = Cm  + (size_t)131072;                    //  3,145,728 (3 cls; cls1 P unused)
    float* S   = P   + (size_t)3145728;                   //  3,145,728
    float* Hin = S   + (size_t)3145728;                   //  4,194,304 (4 dirs)
    float* yAB = Hin + (size_t)4194304;                   //  2,097,152
    float* yC  = yAB + (size_t)2097152;                   //  2,097,152

    k1_mfma<<<1024, 256, 0, stream>>>(feat, Wd, bd, WB, WC, du, Bm, Cm);
    p1_aggr<<<512, 256, 0, stream>>>(du, Bm, A_log, P, S);
    p2_scan<<<256, 128, 0, stream>>>(P, S, Hin);
    p3_replay<<<512, 256, 0, stream>>>(du, Bm, Cm, A_log, Hin, yAB, yC);
    k6_reduce<<<512, 256, 0, stream>>>(feat, D, yAB, yC, out);
}

// Round 6
// 149.681 us; speedup vs baseline: 2.8826x; 1.2288x over previous
//
#include <hip/hip_runtime.h>
#include <cstdint>
#include <cstddef>

#define BB 2
#define CC 256
#define NN 16
#define LL 4096
#define NCH 128
#define CLEN 32
#define LOG2E 1.4426950408889634f

typedef __attribute__((ext_vector_type(8))) short short8;
typedef __attribute__((ext_vector_type(4))) float f32x4;

__device__ __forceinline__ float softplus_f(float z) {
    return fmaxf(z, 0.f) + log1pf(expf(-fabsf(z)));
}

__device__ __forceinline__ uint32_t pack_bf2(float d, float u) {
    uint32_t lo = (__float_as_uint(d) + 0x8000u) >> 16;
    uint32_t hh = (__float_as_uint(u) + 0x8000u) & 0xffff0000u;
    return hh | lo;
}

__device__ __forceinline__ short bf16r(float f) {
    return (short)((__float_as_uint(f) + 0x8000u) >> 16);
}

// ---------------- K1 (MFMA): Z = X@Wd via bf16 matrix cores -----------------
__global__ __launch_bounds__(256) void k1_mfma(
    const float* __restrict__ feat, const float* __restrict__ Wd,
    const float* __restrict__ bd, const float* __restrict__ WB,
    const float* __restrict__ WC, uint32_t* __restrict__ du,
    float* __restrict__ Bm, float* __restrict__ Cm)
{
    int blk = blockIdx.x;               // b*512 + lt*4 + ct
    int b  = blk >> 9;
    int lt = (blk >> 2) & 127;
    int ct = blk & 3;
    int l0 = lt * 32, c0 = ct * 64;
    const float* fbase = feat + (size_t)b * CC * LL;
    int lane = threadIdx.x & 63;
    int wq   = threadIdx.x >> 6;
    int m    = lane & 15;
    int quad = lane >> 4;
    int m0   = (wq & 1) * 16;
    int n0   = (wq >> 1) * 32;
    bool doBC = (ct == 0);
    const float* wBC = (wq >> 1) ? WC : WB;

    f32x4 acc0 = {0.f, 0.f, 0.f, 0.f};
    f32x4 acc1 = {0.f, 0.f, 0.f, 0.f};
    f32x4 accB = {0.f, 0.f, 0.f, 0.f};

    const float* aptr  = fbase + (size_t)(quad * 8) * LL + (l0 + m0 + m);
    const float* b0ptr = Wd    + (size_t)(quad * 8) * CC + (c0 + n0 + m);
    const float* b1ptr = b0ptr + 16;
    const float* bbptr = wBC   + (size_t)(quad * 8) * NN + m;

    for (int ks = 0; ks < 8; ++ks) {
        short8 af, bf0, bf1;
        #pragma unroll
        for (int j = 0; j < 8; ++j) {
            size_t kr = (size_t)(ks * 32 + j);
            af[j]  = bf16r(aptr [kr * LL]);
            bf0[j] = bf16r(b0ptr[kr * CC]);
            bf1[j] = bf16r(b1ptr[kr * CC]);
        }
        acc0 = __builtin_amdgcn_mfma_f32_16x16x32_bf16(af, bf0, acc0, 0, 0, 0);
        acc1 = __builtin_amdgcn_mfma_f32_16x16x32_bf16(af, bf1, acc1, 0, 0, 0);
        if (doBC) {
            short8 bbf;
            #pragma unroll
            for (int j = 0; j < 8; ++j)
                bbf[j] = bf16r(bbptr[(size_t)(ks * 32 + j) * NN]);
            accB = __builtin_amdgcn_mfma_f32_16x16x32_bf16(af, bbf, accB, 0, 0, 0);
        }
    }

    if (doBC) {
        float* dst = (wq >> 1) ? Cm : Bm;
        #pragma unroll
        for (int r = 0; r < 4; ++r) {
            int l = l0 + m0 + quad * 4 + r;
            dst[((size_t)b * LL + l) * NN + m] = accB[r];
        }
    }

    float bd0 = bd[c0 + n0 + m];
    float bd1 = bd[c0 + n0 + 16 + m];
    int cA = c0 + n0 + m;
    int cB = cA + 16;
    #pragma unroll
    for (int r = 0; r < 4; ++r) {
        int l = l0 + m0 + quad * 4 + r;
        float d0 = softplus_f(acc0[r] + bd0);
        float d1 = softplus_f(acc1[r] + bd1);
        float x0 = fbase[(size_t)cA * LL + l];
        float x1 = fbase[(size_t)cB * LL + l];
        du[((size_t)b * LL + l) * CC + cA] = pack_bf2(d0, d0 * x0);
        du[((size_t)b * LL + l) * CC + cB] = pack_bf2(d1, d1 * x1);
    }
}

// ---------------- P1: per-chunk aggregates ----------------------------------
// R3 post-mortem fix: w[] lives in an LDS private slot (sW[j*256+c]; each
// thread touches only its own column -> conflict-free, NO barrier needed),
// loaded by a short unrolled prologue. The j-loops then run UN-unrolled
// (#pragma unroll 1): no runtime-indexed register array (rule #20), body
// ~100 instrs instead of ~3K, live set ~100 VGPR -> no scratch spill.
__global__ __launch_bounds__(256) void p1_aggr(
    const uint32_t* __restrict__ du, const float* __restrict__ Bm,
    const float* __restrict__ A_log, float* __restrict__ P, float* __restrict__ S)
{
    int blk = blockIdx.x;
    int b  = (blk >> 7) & 1;
    int ch = blk & 127;
    int c = threadIdx.x;
    __shared__ float sBm[CLEN * NN];
    __shared__ uint32_t sW[CLEN * 256];

    float A2[NN];
    {
        const float4* al = (const float4*)(A_log + c * NN);
        #pragma unroll
        for (int q = 0; q < 4; ++q) {
            float4 v = al[q];
            A2[q*4+0] = -expf(v.x) * LOG2E;
            A2[q*4+1] = -expf(v.y) * LOG2E;
            A2[q*4+2] = -expf(v.z) * LOG2E;
            A2[q*4+3] = -expf(v.w) * LOG2E;
        }
    }

    if (blk < 256) {
        int p0 = 32 * ch;
        for (int i = threadIdx.x; i < CLEN * NN; i += 256) {
            int j = i >> 4, nn = i & 15;
            sBm[i] = Bm[((size_t)b * LL + (p0 + j)) * NN + nn];
        }
        const uint32_t* dub = du + (size_t)b * LL * CC + c;
        {   // prologue: batch the 32 global loads (one latency exposure),
            // then park them in the LDS private slot; regs die here.
            uint32_t wt[CLEN];
            #pragma unroll
            for (int j = 0; j < CLEN; ++j) wt[j] = dub[(size_t)(p0 + j) * CC];
            #pragma unroll
            for (int j = 0; j < CLEN; ++j) sW[j * 256 + c] = wt[j];
        }
        __syncthreads();
        float Sf[NN] = {}, Sr[NN] = {}, pref[NN];
        #pragma unroll
        for (int nn = 0; nn < NN; ++nn) pref[nn] = 1.f;
        float sumd = 0.f;
        #pragma unroll 1
        for (int j = 0; j < CLEN; ++j) {
            uint32_t wj = sW[j * 256 + c];
            float dx = __uint_as_float(wj << 16);
            float uy = __uint_as_float(wj & 0xffff0000u);
            sumd += dx;
            float dA[NN];
            #pragma unroll
            for (int nn = 0; nn < NN; ++nn) dA[nn] = __builtin_amdgcn_exp2f(A2[nn] * dx);
            #pragma unroll
            for (int nn = 0; nn < NN; ++nn) {
                float Bu = uy * sBm[j * 16 + nn];
                Sf[nn] = fmaf(dA[nn], Sf[nn], Bu);
                Sr[nn] = fmaf(pref[nn], Bu, Sr[nn]);
                pref[nn] *= dA[nn];
            }
        }
        size_t base0 = ((size_t)(b * 128 + ch)) * 4096 + (size_t)c * 16;
        size_t base1 = ((size_t)((2 + b) * 128 + (127 - ch))) * 4096 + (size_t)c * 16;
        #pragma unroll
        for (int nn = 0; nn < NN; ++nn) {
            P[base0 + nn] = __builtin_amdgcn_exp2f(A2[nn] * sumd);
            S[base0 + nn] = Sf[nn];
            S[base1 + nn] = Sr[nn];
        }
    } else {
        // cls2: d3 column chunks (inner stride 64)
        int p0 = 63 - (ch >> 1) + 2048 * (ch & 1);
        const int inner = 64;
        for (int i = threadIdx.x; i < CLEN * NN; i += 256) {
            int j = i >> 4, nn = i & 15;
            sBm[i] = Bm[((size_t)b * LL + (p0 + inner * j)) * NN + nn];
        }
        const uint32_t* dub = du + (size_t)b * LL * CC + c;
        {
            uint32_t wt[CLEN];
            #pragma unroll
            for (int j = 0; j < CLEN; ++j) wt[j] = dub[(size_t)(p0 + inner * j) * CC];
            #pragma unroll
            for (int j = 0; j < CLEN; ++j) sW[j * 256 + c] = wt[j];
        }
        __syncthreads();
        float Sv[NN] = {};
        float sumd = 0.f;
        #pragma unroll 1
        for (int j = 0; j < CLEN; ++j) {
            uint32_t wj = sW[j * 256 + c];
            float dx = __uint_as_float(wj << 16);
            float uy = __uint_as_float(wj & 0xffff0000u);
            sumd += dx;
            float dA[NN];
            #pragma unroll
            for (int nn = 0; nn < NN; ++nn) dA[nn] = __builtin_amdgcn_exp2f(A2[nn] * dx);
            #pragma unroll
            for (int nn = 0; nn < NN; ++nn)
                Sv[nn] = fmaf(dA[nn], Sv[nn], uy * sBm[j * 16 + nn]);
        }
        size_t base = ((size_t)((4 + b) * 128 + ch)) * 4096 + (size_t)c * 16;
        #pragma unroll
        for (int nn = 0; nn < NN; ++nn) {
            P[base + nn] = __builtin_amdgcn_exp2f(A2[nn] * sumd);
            S[base + nn] = Sv[nn];
        }
    }
}

// ---------------- P2: scan chunk aggregates per direction -> Hin ------------
__global__ __launch_bounds__(128) void p2_scan(
    const float* __restrict__ P, const float* __restrict__ S, float* __restrict__ Hin)
{
    int r = blockIdx.x * 128 + threadIdx.x;   // 32768 rows
    int cn = r & 4095;
    int db = r >> 12;
    int d = db >> 1;
    int cls = (d == 1) ? 1 : ((d == 3) ? 2 : 0);
    int b = db & 1;
    const size_t sbase = ((size_t)(cls * 2 + b) * 128) * 4096 + cn;
    const size_t pbase = (d == 1) ? (((size_t)b * 128) * 4096 + cn) : sbase;
    const size_t obase = ((size_t)db * 128) * 4096 + cn;
    float h = 0.f;
    for (int g = 0; g < 16; ++g) {
        float pv[8], sv[8];
        #pragma unroll
        for (int i = 0; i < 8; ++i) {
            int ch = g * 8 + i;
            int chm = (d == 2) ? (126 - 2 * (ch >> 1) + (ch & 1)) : ch;
            int chp = (d == 1) ? (127 - ch) : chm;
            pv[i] = P[pbase + (size_t)chp * 4096];
            sv[i] = S[sbase + (size_t)chm * 4096];
        }
        #pragma unroll
        for (int i = 0; i < 8; ++i) {
            Hin[obase + (size_t)(g * 8 + i) * 4096] = h;
            h = fmaf(pv[i], h, sv[i]);
        }
    }
}

// ---------------- P3: replay ------------------------------------------------
// FUSED d0+d2 (fwd) + d1 (bwd) on one du/Bm/Cm read (blk<256); d3 (blk>=256).
// R3 fix (VGPR was 256 + 19MB scratch spill from fully-unrolled 32-step
// loops): w -> LDS private slot sW, y1 -> LDS private slot sY (both
// own-column, conflict-free, barrier-free), j-loops UN-unrolled. Live set
// per loop: bwd A2+h1+dA=48, fwd A2+h0+h2+dA=64 VGPRs.
// LDS = 2+2+32+32 = 68 KB -> 2 blocks/CU (grid is 2/CU anyway).
__global__ __launch_bounds__(256) void p3_replay(
    const uint32_t* __restrict__ du, const float* __restrict__ Bm,
    const float* __restrict__ Cm, const float* __restrict__ A_log,
    const float* __restrict__ Hin, float* __restrict__ yAB,
    float* __restrict__ yC)
{
    int blk = blockIdx.x;
    int b  = (blk >> 7) & 1;
    int ch = blk & 127;
    int c = threadIdx.x;
    __shared__ float sBm[CLEN * NN];
    __shared__ float sCm[CLEN * NN];
    __shared__ uint32_t sW[CLEN * 256];
    __shared__ float sY[CLEN * 256];

    float A2[NN];
    {
        const float4* al = (const float4*)(A_log + c * NN);
        #pragma unroll
        for (int q = 0; q < 4; ++q) {
            float4 v = al[q];
            A2[q*4+0] = -expf(v.x) * LOG2E;
            A2[q*4+1] = -expf(v.y) * LOG2E;
            A2[q*4+2] = -expf(v.z) * LOG2E;
            A2[q*4+3] = -expf(v.w) * LOG2E;
        }
    }

    if (blk < 256) {
        int p0 = 32 * ch;
        for (int i = threadIdx.x; i < CLEN * NN; i += 256) {
            int j = i >> 4, nn = i & 15;
            size_t o = ((size_t)b * LL + (p0 + j)) * NN + nn;
            sBm[i] = Bm[o];
            sCm[i] = Cm[o];
        }
        const uint32_t* dub = du + (size_t)b * LL * CC + c;
        {
            uint32_t wt[CLEN];
            #pragma unroll
            for (int j = 0; j < CLEN; ++j) wt[j] = dub[(size_t)(p0 + j) * CC];
            #pragma unroll
            for (int j = 0; j < CLEN; ++j) sW[j * 256 + c] = wt[j];
        }

        // --- backward pass: d1 (l decreasing == j 31..0); only h1 live ---
        int chr = 127 - ch;                     // d1 chunk covering same l-set
        float h1[NN];
        {
            const float4* hp1 = (const float4*)(Hin + ((size_t)(1 * 2 + b) * 128 + chr) * 4096 + (size_t)c * 16);
            #pragma unroll
            for (int q = 0; q < 4; ++q) {
                float4 v1 = hp1[q];
                h1[q*4+0]=v1.x; h1[q*4+1]=v1.y; h1[q*4+2]=v1.z; h1[q*4+3]=v1.w;
            }
        }
        __syncthreads();    // sBm/sCm cooperative load complete
        #pragma unroll 1
        for (int j = CLEN - 1; j >= 0; --j) {
            uint32_t wj = sW[j * 256 + c];
            float dx = __uint_as_float(wj << 16);
            float uy = __uint_as_float(wj & 0xffff0000u);
            float dA[NN];
            #pragma unroll
            for (int nn = 0; nn < NN; ++nn) dA[nn] = __builtin_amdgcn_exp2f(A2[nn] * dx);
            float yv = 0.f;
            #pragma unroll
            for (int nn = 0; nn < NN; ++nn) {
                float Bu = uy * sBm[j * 16 + nn];
                h1[nn] = fmaf(dA[nn], h1[nn], Bu);
                yv = fmaf(h1[nn], sCm[j * 16 + nn], yv);
            }
            sY[j * 256 + c] = yv;    // own slot; no barrier needed
        }

        // --- forward pass: d0 + d2; h1 dead, load h0/h2 now ---
        int ch2 = 126 - (ch & ~1) + (ch & 1);   // d2 scan-position of this chunk
        float h0[NN], h2[NN];
        {
            const float4* hp0 = (const float4*)(Hin + ((size_t)(0 * 2 + b) * 128 + ch)  * 4096 + (size_t)c * 16);
            const float4* hp2 = (const float4*)(Hin + ((size_t)(2 * 2 + b) * 128 + ch2) * 4096 + (size_t)c * 16);
            #pragma unroll
            for (int q = 0; q < 4; ++q) {
                float4 v0 = hp0[q], v2 = hp2[q];
                h0[q*4+0]=v0.x; h0[q*4+1]=v0.y; h0[q*4+2]=v0.z; h0[q*4+3]=v0.w;
                h2[q*4+0]=v2.x; h2[q*4+1]=v2.y; h2[q*4+2]=v2.z; h2[q*4+3]=v2.w;
            }
        }
        #pragma unroll 1
        for (int j = 0; j < CLEN; ++j) {
            uint32_t wj = sW[j * 256 + c];
            float dx = __uint_as_float(wj << 16);
            float uy = __uint_as_float(wj & 0xffff0000u);
            float dA[NN];
            #pragma unroll
            for (int nn = 0; nn < NN; ++nn) dA[nn] = __builtin_amdgcn_exp2f(A2[nn] * dx);
            float y0v = 0.f, y2v = 0.f;
            #pragma unroll
            for (int nn = 0; nn < NN; ++nn) {
                float Bu = uy * sBm[j * 16 + nn];
                float cm = sCm[j * 16 + nn];
                h0[nn] = fmaf(dA[nn], h0[nn], Bu);
                h2[nn] = fmaf(dA[nn], h2[nn], Bu);
                y0v = fmaf(h0[nn], cm, y0v);
                y2v = fmaf(h2[nn], cm, y2v);
            }
            yAB[((size_t)b * LL + p0 + j) * CC + c] = 0.25f * (y0v + y2v + sY[j * 256 + c]);
        }
    } else {
        // d3 column replay
        int p0 = 63 - (ch >> 1) + 2048 * (ch & 1);
        const int inner = 64;
        for (int i = threadIdx.x; i < CLEN * NN; i += 256) {
            int j = i >> 4, nn = i & 15;
            size_t o = ((size_t)b * LL + (p0 + inner * j)) * NN + nn;
            sBm[i] = Bm[o];
            sCm[i] = Cm[o];
        }
        const uint32_t* dub = du + (size_t)b * LL * CC + c;
        {
            uint32_t wt[CLEN];
            #pragma unroll
            for (int j = 0; j < CLEN; ++j) wt[j] = dub[(size_t)(p0 + inner * j) * CC];
            #pragma unroll
            for (int j = 0; j < CLEN; ++j) sW[j * 256 + c] = wt[j];
        }
        float h[NN];
        {
            const float4* hp = (const float4*)(Hin + ((size_t)(3 * 2 + b) * 128 + ch) * 4096 + (size_t)c * 16);
            #pragma unroll
            for (int q = 0; q < 4; ++q) {
                float4 v = hp[q];
                h[q*4+0]=v.x; h[q*4+1]=v.y; h[q*4+2]=v.z; h[q*4+3]=v.w;
            }
        }
        __syncthreads();
        #pragma unroll 1
        for (int j = 0; j < CLEN; ++j) {
            uint32_t wj = sW[j * 256 + c];
            float dx = __uint_as_float(wj << 16);
            float uy = __uint_as_float(wj & 0xffff0000u);
            float dA[NN];
            #pragma unroll
            for (int nn = 0; nn < NN; ++nn) dA[nn] = __builtin_amdgcn_exp2f(A2[nn] * dx);
            float yv = 0.f;
            #pragma unroll
            for (int nn = 0; nn < NN; ++nn) {
                float Bu = uy * sBm[j * 16 + nn];
                h[nn] = fmaf(dA[nn], h[nn], Bu);
                yv = fmaf(h[nn], sCm[j * 16 + nn], yv);
            }
            yC[((size_t)b * LL + p0 + inner * j) * CC + c] = 0.25f * yv;
        }
    }
}

// ---------------- K6: sum 2 y-buffers + x*D, transpose to (B,C,L) -----------
__global__ __launch_bounds__(256) void k6_reduce(
    const float* __restrict__ feat, const float* __restrict__ D,
    const float* __restrict__ yAB, const float* __restrict__ yC,
    float* __restrict__ out)
{
    int pt = blockIdx.x & 63;
    int ct = (blockIdx.x >> 6) & 3;
    int b  = blockIdx.x >> 8;
    int p0 = pt * 64, c0 = ct * 64;
    __shared__ float tile[64 * 65];
    {
        int cl = threadIdx.x & 63;
        int pg = threadIdx.x >> 6;
        #pragma unroll
        for (int pp = 0; pp < 16; ++pp) {
            int pl = pp * 4 + pg;
            size_t ix = ((size_t)b * LL + p0 + pl) * CC + c0 + cl;
            tile[cl * 65 + pl] = yAB[ix] + yC[ix];
        }
    }
    __syncthreads();
    {
        int pl = threadIdx.x & 63;
        int cg = threadIdx.x >> 6;
        #pragma unroll
        for (int cc = 0; cc < 16; ++cc) {
            int cloc = cc * 4 + cg;
            int c = c0 + cloc;
            size_t o = ((size_t)b * CC + c) * LL + p0 + pl;
            out[o] = tile[cloc * 65 + pl] + feat[o] * D[c];
        }
    }
}

extern "C" void kernel_launch(void* const* d_in, const int* in_sizes, int n_in,
                              void* d_out, int out_size, void* d_ws, size_t ws_size,
                              hipStream_t stream)
{
    const float* feat  = (const float*)d_in[0];
    const float* A_log = (const float*)d_in[1];
    const float* D     = (const float*)d_in[2];
    const float* Wd    = (const float*)d_in[3];
    const float* bd    = (const float*)d_in[4];
    const float* WB    = (const float*)d_in[5];
    const float* WC    = (const float*)d_in[6];
    float* out = (float*)d_out;

    float* ws  = (float*)d_ws;
    uint32_t* du = (uint32_t*)ws;                         //  2,097,152 u32 (bf16x2)
    float* Bm  = ws  + (size_t)2097152;                   //    131,072
    float* Cm  = Bm  + (size_t)131072;                    //    131,072
    float* P   = Cm  + (size_t)131072;                    //  3,145,728 (3 cls; cls1 P unused)
    float* S   = P   + (size_t)3145728;                   //  3,145,728
    float* Hin = S   + (size_t)3145728;                   //  4,194,304 (4 dirs)
    float* yAB = Hin + (size_t)4194304;                   //  2,097,152
    float* yC  = yAB + (size_t)2097152;                   //  2,097,152

    k1_mfma<<<1024, 256, 0, stream>>>(feat, Wd, bd, WB, WC, du, Bm, Cm);
    p1_aggr<<<512, 256, 0, stream>>>(du, Bm, A_log, P, S);
    p2_scan<<<256, 128, 0, stream>>>(P, S, Hin);
    p3_replay<<<512, 256, 0, stream>>>(du, Bm, Cm, A_log, Hin, yAB, yC);
    k6_reduce<<<512, 256, 0, stream>>>(feat, D, yAB, yC, out);
}